// Round 12
// baseline (257.933 us; speedup 1.0000x reference)
//
#include <hip/hip_runtime.h>
#include <hip/hip_bf16.h>

typedef unsigned short u16;
typedef unsigned int u32;
typedef __bf16 bf16x8 __attribute__((ext_vector_type(8)));
typedef float f32x4 __attribute__((ext_vector_type(4)));
typedef u16 u16x4 __attribute__((ext_vector_type(4)));
typedef u16 u16x8 __attribute__((ext_vector_type(8)));

#define N_    4096
#define H_    16
#define BH_   64
#define DIM_  1024
#define MTOK  16384

// global row bases (row = 64 bf16 elements): 64*cumn[l]
#define RB1 262144
#define RB2 393216
#define RB3 458752
#define RB4 491520
#define RB5 507904
#define RB6 516096

__device__ __forceinline__ float bf2f(u16 u) {
  union { u32 i; float f; } x; x.i = ((u32)u) << 16; return x.f;
}
__device__ __forceinline__ u16 f2bf(float f) {
  union { float f; u32 i; } x; x.f = f;
  u32 r = x.i + 0x7fffu + ((x.i >> 16) & 1u);
  return (u16)(r >> 16);
}

__device__ __forceinline__ void gload_lds16(const u16* g, u16* l) {
  __builtin_amdgcn_global_load_lds(
      (const __attribute__((address_space(1))) void*)g,
      (__attribute__((address_space(3))) void*)l, 16, 0, 0);
}

// ---------------- prep: hid fp32->bf16 (blocks 0..16383) + W transpose (blocks 16384+) ----
__global__ __launch_bounds__(256) void k_prep(const float* __restrict__ hid,
                                              u16* __restrict__ hidb,
                                              const float* __restrict__ Wq,
                                              const float* __restrict__ Wk,
                                              const float* __restrict__ Wv,
                                              u16* __restrict__ Wt) {
  __shared__ float tile[32][33];
  const int bx = blockIdx.x;
  if (bx < 16384) {
    int i = bx * 256 + threadIdx.x;   // exactly MTOK*DIM/4 elements
    f32x4 v = reinterpret_cast<const f32x4*>(hid)[i];
    u16x4 o;
    o[0] = f2bf(v[0]); o[1] = f2bf(v[1]); o[2] = f2bf(v[2]); o[3] = f2bf(v[3]);
    reinterpret_cast<u16x4*>(hidb)[i] = o;
  } else {
    const int bid = bx - 16384;       // 0..3071
    const int zz = bid >> 10;
    const int rem = bid & 1023;
    const int n0 = (rem & 31) * 32, k0 = (rem >> 5) * 32;
    const float* W = (zz == 0) ? Wq : ((zz == 1) ? Wk : Wv);
    const int tx = threadIdx.x & 31, ty = threadIdx.x >> 5;
    #pragma unroll
    for (int r = ty; r < 32; r += 8)
      tile[r][tx] = W[(size_t)(k0 + r) * DIM_ + n0 + tx];
    __syncthreads();
    u16* o = Wt + (size_t)zz * DIM_ * DIM_;
    #pragma unroll
    for (int r = ty; r < 32; r += 8)
      o[(size_t)(n0 + r) * DIM_ + k0 + tx] = f2bf(tile[tx][r]);
  }
}

// ---------------- fused QKV GEMM: ONE block computes q,k,v for its 128x128 tile ----
// A-tile staged once per K-step, shared by 3 B-tiles -> 96 MFMA per barrier pair.
// Epilogue (n outer, m inner): bias+scale, L0 store, and ALL coarsen levels L1-L6
// (L5/L6 from in-lane c4 sums across the wave's 4 m-fragments).
__global__ __launch_bounds__(256, 2) void k_qkv_gemm(
    const u16* __restrict__ hid,   // [16384][1024] bf16
    const u16* __restrict__ Wt,    // [3][1024][1024] bf16, n-major (W^T)
    const float* __restrict__ bq, const float* __restrict__ bk, const float* __restrict__ bv,
    u16* __restrict__ qout, u16* __restrict__ kout, u16* __restrict__ vout) {
  const int m0 = blockIdx.x * 128;
  const int n0 = blockIdx.y * 128;
  __shared__ u16 As[128 * 64];
  __shared__ u16 Bs[3][128 * 64];
  const int t = threadIdx.x;
  const int lane = t & 63, wave = t >> 6;
  const int wm = (wave >> 1) * 64, wn = (wave & 1) * 64;
  f32x4 acc[3][4][4];
  #pragma unroll
  for (int z = 0; z < 3; z++)
    #pragma unroll
    for (int m = 0; m < 4; m++)
      #pragma unroll
      for (int n = 0; n < 4; n++) acc[z][m][n] = (f32x4){0.f, 0.f, 0.f, 0.f};

  const int srow = t >> 3;
  const int sslot = (t & 7) ^ (srow & 7);
  const u16* Ag = hid + ((size_t)m0 + srow) * DIM_ + sslot * 8;
  const u16* Bg = Wt + ((size_t)n0 + srow) * DIM_ + sslot * 8;
  u16* AsT = &As[t * 8];
  const int lr = lane & 15, kg = lane >> 4;

  for (int k0 = 0; k0 < DIM_; k0 += 64) {
    #pragma unroll
    for (int j = 0; j < 4; j++)
      gload_lds16(Ag + k0 + j * (32 * DIM_), AsT + j * 2048);
    #pragma unroll
    for (int z = 0; z < 3; z++)
      #pragma unroll
      for (int j = 0; j < 4; j++)
        gload_lds16(Bg + (size_t)z * DIM_ * DIM_ + k0 + j * (32 * DIM_),
                    &Bs[z][t * 8 + j * 2048]);
    __syncthreads();
    #pragma unroll
    for (int ks = 0; ks < 2; ks++) {
      const int sw = ((ks * 4 + kg) ^ (lr & 7)) * 8;
      bf16x8 af[4];
      #pragma unroll
      for (int m = 0; m < 4; m++)
        af[m] = *reinterpret_cast<const bf16x8*>(&As[(wm + m * 16 + lr) * 64 + sw]);
      #pragma unroll
      for (int z = 0; z < 3; z++) {
        bf16x8 bfr[4];
        #pragma unroll
        for (int n = 0; n < 4; n++)
          bfr[n] = *reinterpret_cast<const bf16x8*>(&Bs[z][(wn + n * 16 + lr) * 64 + sw]);
        #pragma unroll
        for (int m = 0; m < 4; m++)
          #pragma unroll
          for (int n = 0; n < 4; n++)
            acc[z][m][n] =
                __builtin_amdgcn_mfma_f32_16x16x32_bf16(af[m], bfr[n], acc[z][m][n], 0, 0, 0);
      }
    }
    __syncthreads();
  }

  const int rg = lane >> 4;
  const int b = m0 >> 12;
  const int posb = m0 & (N_ - 1);
  const int h = (n0 + wn) >> 6;        // one head per wave (wn in {0,64})
  const size_t bh = (size_t)(b * H_ + h);

  #pragma unroll
  for (int z = 0; z < 3; z++) {
    const float* bias = (z == 0) ? bq : ((z == 1) ? bk : bv);
    u16* dst = (z == 0) ? qout : ((z == 1) ? kout : vout);
    const float scale = (z == 0) ? 0.125f : 1.0f;  // DH^-0.5
    const bool isv = (z == 2);
    const float s1 = isv ? 1.f : 0.5f, s2 = isv ? 1.f : 0.25f;
    const float s3 = isv ? 1.f : 0.125f, s4 = isv ? 1.f : 0.0625f;
    const float s5 = isv ? 1.f : 0.03125f, s6 = isv ? 1.f : 0.015625f;
    #pragma unroll
    for (int n = 0; n < 4; n++) {
      const int d = n * 16 + lr;
      const float bias_v = bias[n0 + wn + d];
      float c5p0 = 0.f, c5p1 = 0.f;
      #pragma unroll
      for (int m = 0; m < 4; m++) {
        const int plm = wm + m * 16;   // fragment pos base (multiple of 16)
        float v0 = (acc[z][m][n][0] + bias_v) * scale;
        float v1 = (acc[z][m][n][1] + bias_v) * scale;
        float v2 = (acc[z][m][n][2] + bias_v) * scale;
        float v3 = (acc[z][m][n][3] + bias_v) * scale;
        const int pl = plm + rg * 4;
        // L0
        size_t r0 = (bh * N_ + posb + pl) * 64 + d;
        dst[r0] = f2bf(v0); dst[r0 + 64] = f2bf(v1);
        dst[r0 + 128] = f2bf(v2); dst[r0 + 192] = f2bf(v3);
        // L1: row pairs, in-lane
        float c1a = v0 + v1, c1b = v2 + v3;
        size_t r1 = ((size_t)RB1 + bh * 2048 + (size_t)((posb + pl) >> 1)) * 64 + d;
        dst[r1] = f2bf(c1a * s1);
        dst[r1 + 64] = f2bf(c1b * s1);
        // L2: 4-row group, in-lane
        float c2 = c1a + c1b;
        dst[((size_t)RB2 + bh * 1024 + (size_t)((posb + pl) >> 2)) * 64 + d] = f2bf(c2 * s2);
        // L3: 8 rows (rg pair via shfl), L4: 16 rows
        float c3 = c2 + __shfl_xor(c2, 16);
        float c4 = c3 + __shfl_xor(c3, 32);
        if ((rg & 1) == 0)
          dst[((size_t)RB3 + bh * 512 + (size_t)(((posb + plm) >> 3) + (rg >> 1))) * 64 + d] =
              f2bf(c3 * s3);
        if (rg == 0)
          dst[((size_t)RB4 + bh * 256 + (size_t)((posb + plm) >> 4)) * 64 + d] = f2bf(c4 * s4);
        // accumulate for L5/L6 (c4 is wave-uniform per column after the shfls)
        if (m < 2) c5p0 += c4; else c5p1 += c4;
      }
      if (rg == 0) {
        const int r5 = (posb + wm) >> 5;
        dst[((size_t)RB5 + bh * 128 + (size_t)r5) * 64 + d] = f2bf(c5p0 * s5);
        dst[((size_t)RB5 + bh * 128 + (size_t)(r5 + 1)) * 64 + d] = f2bf(c5p1 * s5);
        dst[((size_t)RB6 + bh * 64 + (size_t)((posb + wm) >> 6)) * 64 + d] =
            f2bf((c5p0 + c5p1) * s6);
      }
    }
  }
}

// ---------------- MFMA attention core ----------------
// One wave handles one 16-row attention block.
// S^T = mfma(K-frag, Q-frag): lane holds S[q=lane&15][kv=(lane>>4)*4+i].
__device__ __forceinline__ void qk_softmax(const u16* __restrict__ qb_, size_t qrow,
                                           const u16* __restrict__ kb_, size_t kvrow,
                                           int lane, f32x4& p, float& asum) {
  const int lr = lane & 15, g = lane >> 4;
  const u16* kp = kb_ + (kvrow + lr) * 64 + g * 8;
  const u16* qp = qb_ + (qrow + lr) * 64 + g * 8;
  bf16x8 ka0 = *reinterpret_cast<const bf16x8*>(kp);
  bf16x8 ka1 = *reinterpret_cast<const bf16x8*>(kp + 32);
  bf16x8 qa0 = *reinterpret_cast<const bf16x8*>(qp);
  bf16x8 qa1 = *reinterpret_cast<const bf16x8*>(qp + 32);
  f32x4 s = (f32x4){0.f, 0.f, 0.f, 0.f};
  s = __builtin_amdgcn_mfma_f32_16x16x32_bf16(ka0, qa0, s, 0, 0, 0);
  s = __builtin_amdgcn_mfma_f32_16x16x32_bf16(ka1, qa1, s, 0, 0, 0);
  float mx = fmaxf(fmaxf(s[0], s[1]), fmaxf(s[2], s[3]));
  mx = fmaxf(mx, __shfl_xor(mx, 16));
  mx = fmaxf(mx, __shfl_xor(mx, 32));
  #pragma unroll
  for (int i = 0; i < 4; i++) p[i] = __expf(s[i] - mx);
  asum = p[0] + p[1] + p[2] + p[3];
  asum += __shfl_xor(asum, 16);
  asum += __shfl_xor(asum, 32);
}

// Gather P into the B-operand layout for zero-padded K=32 PV MFMA.
__device__ __forceinline__ bf16x8 prep_pb(const f32x4& p, int lane) {
  const int g = lane >> 4;
  const int src = (lane & 15) + ((g & 1) << 5);
  float tl[4], th[4];
  #pragma unroll
  for (int i = 0; i < 4; i++) {
    tl[i] = __shfl(p[i], src);
    th[i] = __shfl(p[i], src + 16);
  }
  const bool act = (g < 2);
  union { u16 u[8]; bf16x8 b; } cvt;
  #pragma unroll
  for (int i = 0; i < 4; i++) {
    cvt.u[i] = act ? f2bf(tl[i]) : (u16)0;
    cvt.u[4 + i] = act ? f2bf(th[i]) : (u16)0;
  }
  return cvt.b;
}

// PV for one 16-wide d chunk: y[i] = Y[q=lane&15][d=c*16+(lane>>4)*4+i]
__device__ __forceinline__ f32x4 pv_chunk(const u16* __restrict__ vb_, size_t kvrow,
                                          int c, int lane, bf16x8 pb) {
  const int lr = lane & 15, g = lane >> 4;
  const u16* vp = vb_ + (kvrow + (size_t)(g & 1) * 8) * 64 + c * 16 + lr;
  union { u16 u[8]; bf16x8 b; } va;
  #pragma unroll
  for (int e = 0; e < 8; e++) va.u[e] = vp[(size_t)e * 64];
  f32x4 y = (f32x4){0.f, 0.f, 0.f, 0.f};
  return __builtin_amdgcn_mfma_f32_16x16x32_bf16(va.b, pb, y, 0, 0, 0);
}

// ---------------- attention levels 1..6, one wave per 16-row block ----------------
__global__ __launch_bounds__(256) void k_attn_rest(
    const u16* __restrict__ qb, const u16* __restrict__ kb, const u16* __restrict__ vb,
    u16* __restrict__ Yb, float* __restrict__ Ab) {
  const int wid = blockIdx.x * 4 + (threadIdx.x >> 6);  // 0..16127
  const int lane = threadIdx.x & 63;
  const int rb = wid * 16;                              // packed row base (levels 1..6)
  int r = rb, lnl = 11;
  while (r >= (64 << lnl)) { r -= (64 << lnl); --lnl; }
  const int posl = r & ((1 << lnl) - 1);                // block-aligned pos
  const size_t qrow = (size_t)RB1 + rb;
  const size_t kvrow = qrow - posl + ((size_t)((((posl >> 4) ^ 1)) & ((1 << (lnl - 4)) - 1)) << 4);

  f32x4 p; float asum;
  qk_softmax(qb, qrow, kb, kvrow, lane, p, asum);
  if (lane < 16) Ab[rb + lane] = asum;
  bf16x8 pb = prep_pb(p, lane);

  const int lr = lane & 15, g = lane >> 4;
  #pragma unroll
  for (int c = 0; c < 4; c++) {
    f32x4 y = pv_chunk(vb, kvrow, c, lane, pb);
    u16x4 o;
    #pragma unroll
    for (int i = 0; i < 4; i++) o[i] = f2bf(y[i]);
    *reinterpret_cast<u16x4*>(Yb + (size_t)(rb + lr) * 64 + c * 16 + g * 4) = o;
  }
}

// ---------------- attention level 0 fused with combine, one wave per block --------
__global__ __launch_bounds__(256) void k_attn0(
    const u16* __restrict__ qb, const u16* __restrict__ kb, const u16* __restrict__ vb,
    const u16* __restrict__ Yb, const float* __restrict__ Ab, float* __restrict__ out) {
  const int wid = blockIdx.x * 4 + (threadIdx.x >> 6);  // 0..16383
  const int lane = threadIdx.x & 63;
  const int rb = wid * 16;
  const int bh = rb >> 12, posb = rb & 4095;
  const size_t qrow = (size_t)rb, kvrow = (size_t)rb;   // L0: diagonal block

  f32x4 p; float asum;
  qk_softmax(qb, qrow, kb, kvrow, lane, p, asum);
  bf16x8 pb = prep_pb(p, lane);

  const int lr = lane & 15, g = lane >> 4;
  const int pos = posb + lr;                            // this lane's q-row position
  float den = asum + 1e-8f;
  int ybase[6];
  #pragma unroll
  for (int l = 1; l <= 6; l++) {
    int st = 262144 - (262144 >> (l - 1));              // packed level-l segment start
    int idx = st + (bh << (12 - l)) + (pos >> l);
    den += Ab[idx];
    ybase[l - 1] = idx;
  }
  const float inv = 1.0f / den;

  const int b = bh >> 4, h = bh & 15;
  float* op = out + ((size_t)(b * N_ + pos)) * DIM_ + h * 64;
  #pragma unroll
  for (int c = 0; c < 4; c++) {
    f32x4 y = pv_chunk(vb, kvrow, c, lane, pb);
    #pragma unroll
    for (int l = 0; l < 6; l++) {
      u16x4 cy = *reinterpret_cast<const u16x4*>(Yb + (size_t)ybase[l] * 64 + c * 16 + g * 4);
      #pragma unroll
      for (int i = 0; i < 4; i++) y[i] += bf2f(cy[i]);
    }
    f32x4 w;
    #pragma unroll
    for (int i = 0; i < 4; i++) w[i] = y[i] * inv;
    *reinterpret_cast<f32x4*>(op + c * 16 + g * 4) = w;
  }
}

extern "C" void kernel_launch(void* const* d_in, const int* in_sizes, int n_in,
                              void* d_out, int out_size, void* d_ws, size_t ws_size,
                              hipStream_t stream) {
  const float* hid = (const float*)d_in[0];
  const float* Wq = (const float*)d_in[1];
  const float* bq = (const float*)d_in[2];
  const float* Wk = (const float*)d_in[3];
  const float* bk = (const float*)d_in[4];
  const float* Wv = (const float*)d_in[5];
  const float* bv = (const float*)d_in[6];
  float* out = (float*)d_out;
  char* ws = (char*)d_ws;

  // workspace (high-water 239,599,616 B):
  //   phase 1 (GEMM):  hidb [0, 33554432)   Wt [33554432, 39845888)
  //   phase 2 (attn):  Yb   [0, 33030144)   Ab [33030144, 34062336)   <- aliases dead hidb/Wt
  //   both:            qb [39845888) kb [106430464) vb [173015040) .. 239599616
  u16* hidb = (u16*)(ws + 0);
  u16* Wt   = (u16*)(ws + 33554432);
  u16* Yb   = (u16*)(ws + 0);           // bf16, levels 1..6 packed (258048 rows x 64)
  float* Ab = (float*)(ws + 33030144);  // fp32, levels 1..6 packed (258048)
  u16* qb   = (u16*)(ws + 39845888);
  u16* kb   = (u16*)(ws + 106430464);
  u16* vb   = (u16*)(ws + 173015040);

  k_prep<<<19456, 256, 0, stream>>>(hid, hidb, Wq, Wk, Wv, Wt);
  k_qkv_gemm<<<dim3(128, 8, 1), 256, 0, stream>>>(hidb, Wt, bq, bk, bv, qb, kb, vb);
  k_attn_rest<<<4032, 256, 0, stream>>>(qb, kb, vb, Yb, Ab);
  k_attn0<<<4096, 256, 0, stream>>>(qb, kb, vb, Yb, Ab, out);
}

// Round 13
// 211.608 us; speedup vs baseline: 1.2189x; 1.2189x over previous
//
#include <hip/hip_runtime.h>
#include <hip/hip_bf16.h>

typedef unsigned short u16;
typedef unsigned int u32;
typedef __bf16 bf16x8 __attribute__((ext_vector_type(8)));
typedef float f32x4 __attribute__((ext_vector_type(4)));
typedef u16 u16x4 __attribute__((ext_vector_type(4)));
typedef u16 u16x8 __attribute__((ext_vector_type(8)));

#define N_    4096
#define H_    16
#define BH_   64
#define DIM_  1024
#define MTOK  16384

// global row bases (row = 64 bf16 elements): 64*cumn[l]
#define RB1 262144
#define RB2 393216
#define RB3 458752
#define RB4 491520
#define RB5 507904
#define RB6 516096

__device__ __forceinline__ float bf2f(u16 u) {
  union { u32 i; float f; } x; x.i = ((u32)u) << 16; return x.f;
}
__device__ __forceinline__ u16 f2bf(float f) {
  union { float f; u32 i; } x; x.f = f;
  u32 r = x.i + 0x7fffu + ((x.i >> 16) & 1u);
  return (u16)(r >> 16);
}

__device__ __forceinline__ void gload_lds16(const u16* g, u16* l) {
  __builtin_amdgcn_global_load_lds(
      (const __attribute__((address_space(1))) void*)g,
      (__attribute__((address_space(3))) void*)l, 16, 0, 0);
}

// ---------------- prep: hid fp32->bf16 (blocks 0..16383) + W transpose (blocks 16384+) ----
__global__ __launch_bounds__(256) void k_prep(const float* __restrict__ hid,
                                              u16* __restrict__ hidb,
                                              const float* __restrict__ Wq,
                                              const float* __restrict__ Wk,
                                              const float* __restrict__ Wv,
                                              u16* __restrict__ Wt) {
  __shared__ float tile[32][33];
  const int bx = blockIdx.x;
  if (bx < 16384) {
    int i = bx * 256 + threadIdx.x;   // exactly MTOK*DIM/4 elements
    f32x4 v = reinterpret_cast<const f32x4*>(hid)[i];
    u16x4 o;
    o[0] = f2bf(v[0]); o[1] = f2bf(v[1]); o[2] = f2bf(v[2]); o[3] = f2bf(v[3]);
    reinterpret_cast<u16x4*>(hidb)[i] = o;
  } else {
    const int bid = bx - 16384;       // 0..3071
    const int zz = bid >> 10;
    const int rem = bid & 1023;
    const int n0 = (rem & 31) * 32, k0 = (rem >> 5) * 32;
    const float* W = (zz == 0) ? Wq : ((zz == 1) ? Wk : Wv);
    const int tx = threadIdx.x & 31, ty = threadIdx.x >> 5;
    #pragma unroll
    for (int r = ty; r < 32; r += 8)
      tile[r][tx] = W[(size_t)(k0 + r) * DIM_ + n0 + tx];
    __syncthreads();
    u16* o = Wt + (size_t)zz * DIM_ * DIM_;
    #pragma unroll
    for (int r = ty; r < 32; r += 8)
      o[(size_t)(n0 + r) * DIM_ + k0 + tx] = f2bf(tile[tx][r]);
  }
}

// ---------------- fused QKV GEMM: ONE block computes q,k,v for its 128x128 tile ----
// A-tile staged once per K-step, shared by 3 B-tiles -> 96 MFMA per barrier pair.
// Epilogue: round-10 order (m outer, n inner; write-coalescing-friendly), L0-L4 as
// before, plus L5/L6 from per-n register accumulators (separate small loop after).
__global__ __launch_bounds__(256, 2) void k_qkv_gemm(
    const u16* __restrict__ hid,   // [16384][1024] bf16
    const u16* __restrict__ Wt,    // [3][1024][1024] bf16, n-major (W^T)
    const float* __restrict__ bq, const float* __restrict__ bk, const float* __restrict__ bv,
    u16* __restrict__ qout, u16* __restrict__ kout, u16* __restrict__ vout) {
  const int m0 = blockIdx.x * 128;
  const int n0 = blockIdx.y * 128;
  __shared__ u16 As[128 * 64];
  __shared__ u16 Bs[3][128 * 64];
  const int t = threadIdx.x;
  const int lane = t & 63, wave = t >> 6;
  const int wm = (wave >> 1) * 64, wn = (wave & 1) * 64;
  f32x4 acc[3][4][4];
  #pragma unroll
  for (int z = 0; z < 3; z++)
    #pragma unroll
    for (int m = 0; m < 4; m++)
      #pragma unroll
      for (int n = 0; n < 4; n++) acc[z][m][n] = (f32x4){0.f, 0.f, 0.f, 0.f};

  const int srow = t >> 3;
  const int sslot = (t & 7) ^ (srow & 7);
  const u16* Ag = hid + ((size_t)m0 + srow) * DIM_ + sslot * 8;
  const u16* Bg = Wt + ((size_t)n0 + srow) * DIM_ + sslot * 8;
  u16* AsT = &As[t * 8];
  const int lr = lane & 15, kg = lane >> 4;

  for (int k0 = 0; k0 < DIM_; k0 += 64) {
    #pragma unroll
    for (int j = 0; j < 4; j++)
      gload_lds16(Ag + k0 + j * (32 * DIM_), AsT + j * 2048);
    #pragma unroll
    for (int z = 0; z < 3; z++)
      #pragma unroll
      for (int j = 0; j < 4; j++)
        gload_lds16(Bg + (size_t)z * DIM_ * DIM_ + k0 + j * (32 * DIM_),
                    &Bs[z][t * 8 + j * 2048]);
    __syncthreads();
    #pragma unroll
    for (int ks = 0; ks < 2; ks++) {
      const int sw = ((ks * 4 + kg) ^ (lr & 7)) * 8;
      bf16x8 af[4];
      #pragma unroll
      for (int m = 0; m < 4; m++)
        af[m] = *reinterpret_cast<const bf16x8*>(&As[(wm + m * 16 + lr) * 64 + sw]);
      #pragma unroll
      for (int z = 0; z < 3; z++) {
        bf16x8 bfr[4];
        #pragma unroll
        for (int n = 0; n < 4; n++)
          bfr[n] = *reinterpret_cast<const bf16x8*>(&Bs[z][(wn + n * 16 + lr) * 64 + sw]);
        #pragma unroll
        for (int m = 0; m < 4; m++)
          #pragma unroll
          for (int n = 0; n < 4; n++)
            acc[z][m][n] =
                __builtin_amdgcn_mfma_f32_16x16x32_bf16(af[m], bfr[n], acc[z][m][n], 0, 0, 0);
      }
    }
    __syncthreads();
  }

  const int rg = lane >> 4;
  const int b = m0 >> 12;
  const int posb = m0 & (N_ - 1);
  const int h = (n0 + wn) >> 6;        // one head per wave (wn in {0,64})
  const size_t bh = (size_t)(b * H_ + h);

  #pragma unroll
  for (int z = 0; z < 3; z++) {
    const float* bias = (z == 0) ? bq : ((z == 1) ? bk : bv);
    u16* dst = (z == 0) ? qout : ((z == 1) ? kout : vout);
    const float scale = (z == 0) ? 0.125f : 1.0f;  // DH^-0.5
    const bool isv = (z == 2);
    const float s1 = isv ? 1.f : 0.5f, s2 = isv ? 1.f : 0.25f;
    const float s3 = isv ? 1.f : 0.125f, s4 = isv ? 1.f : 0.0625f;
    const float s5 = isv ? 1.f : 0.03125f, s6 = isv ? 1.f : 0.015625f;
    float c5a[4], c5b[4];   // per-n L5 partials (unrolled -> registers)
    #pragma unroll
    for (int n = 0; n < 4; n++) { c5a[n] = 0.f; c5b[n] = 0.f; }
    #pragma unroll
    for (int m = 0; m < 4; m++) {
      const int plm = wm + m * 16;     // fragment pos base (multiple of 16)
      #pragma unroll
      for (int n = 0; n < 4; n++) {
        const int d = n * 16 + lr;
        const float bias_v = bias[n0 + wn + d];
        float v0 = (acc[z][m][n][0] + bias_v) * scale;
        float v1 = (acc[z][m][n][1] + bias_v) * scale;
        float v2 = (acc[z][m][n][2] + bias_v) * scale;
        float v3 = (acc[z][m][n][3] + bias_v) * scale;
        const int pl = plm + rg * 4;
        // L0
        size_t r0 = (bh * N_ + posb + pl) * 64 + d;
        dst[r0] = f2bf(v0); dst[r0 + 64] = f2bf(v1);
        dst[r0 + 128] = f2bf(v2); dst[r0 + 192] = f2bf(v3);
        // L1: row pairs, in-lane
        float c1a = v0 + v1, c1b = v2 + v3;
        size_t r1 = ((size_t)RB1 + bh * 2048 + (size_t)((posb + pl) >> 1)) * 64 + d;
        dst[r1] = f2bf(c1a * s1);
        dst[r1 + 64] = f2bf(c1b * s1);
        // L2: 4-row group, in-lane
        float c2 = c1a + c1b;
        dst[((size_t)RB2 + bh * 1024 + (size_t)((posb + pl) >> 2)) * 64 + d] = f2bf(c2 * s2);
        // L3: 8 rows (rg pair via shfl), L4: 16 rows
        float c3 = c2 + __shfl_xor(c2, 16);
        float c4 = c3 + __shfl_xor(c3, 32);
        if ((rg & 1) == 0)
          dst[((size_t)RB3 + bh * 512 + (size_t)(((posb + plm) >> 3) + (rg >> 1))) * 64 + d] =
              f2bf(c3 * s3);
        if (rg == 0)
          dst[((size_t)RB4 + bh * 256 + (size_t)((posb + plm) >> 4)) * 64 + d] = f2bf(c4 * s4);
        // accumulate L5 partials (c4 uniform across rg per column)
        if (m < 2) c5a[n] += c4; else c5b[n] += c4;
      }
    }
    if (rg == 0) {
      const int r5 = (posb + wm) >> 5;
      const int r6 = (posb + wm) >> 6;
      #pragma unroll
      for (int n = 0; n < 4; n++) {
        const int d = n * 16 + lr;
        dst[((size_t)RB5 + bh * 128 + (size_t)r5) * 64 + d] = f2bf(c5a[n] * s5);
        dst[((size_t)RB5 + bh * 128 + (size_t)(r5 + 1)) * 64 + d] = f2bf(c5b[n] * s5);
        dst[((size_t)RB6 + bh * 64 + (size_t)r6) * 64 + d] = f2bf((c5a[n] + c5b[n]) * s6);
      }
    }
  }
}

// ---------------- MFMA attention core ----------------
// One wave handles one 16-row attention block.
// S^T = mfma(K-frag, Q-frag): lane holds S[q=lane&15][kv=(lane>>4)*4+i].
__device__ __forceinline__ void qk_softmax(const u16* __restrict__ qb_, size_t qrow,
                                           const u16* __restrict__ kb_, size_t kvrow,
                                           int lane, f32x4& p, float& asum) {
  const int lr = lane & 15, g = lane >> 4;
  const u16* kp = kb_ + (kvrow + lr) * 64 + g * 8;
  const u16* qp = qb_ + (qrow + lr) * 64 + g * 8;
  bf16x8 ka0 = *reinterpret_cast<const bf16x8*>(kp);
  bf16x8 ka1 = *reinterpret_cast<const bf16x8*>(kp + 32);
  bf16x8 qa0 = *reinterpret_cast<const bf16x8*>(qp);
  bf16x8 qa1 = *reinterpret_cast<const bf16x8*>(qp + 32);
  f32x4 s = (f32x4){0.f, 0.f, 0.f, 0.f};
  s = __builtin_amdgcn_mfma_f32_16x16x32_bf16(ka0, qa0, s, 0, 0, 0);
  s = __builtin_amdgcn_mfma_f32_16x16x32_bf16(ka1, qa1, s, 0, 0, 0);
  float mx = fmaxf(fmaxf(s[0], s[1]), fmaxf(s[2], s[3]));
  mx = fmaxf(mx, __shfl_xor(mx, 16));
  mx = fmaxf(mx, __shfl_xor(mx, 32));
  #pragma unroll
  for (int i = 0; i < 4; i++) p[i] = __expf(s[i] - mx);
  asum = p[0] + p[1] + p[2] + p[3];
  asum += __shfl_xor(asum, 16);
  asum += __shfl_xor(asum, 32);
}

// Gather P into the B-operand layout for zero-padded K=32 PV MFMA.
__device__ __forceinline__ bf16x8 prep_pb(const f32x4& p, int lane) {
  const int g = lane >> 4;
  const int src = (lane & 15) + ((g & 1) << 5);
  float tl[4], th[4];
  #pragma unroll
  for (int i = 0; i < 4; i++) {
    tl[i] = __shfl(p[i], src);
    th[i] = __shfl(p[i], src + 16);
  }
  const bool act = (g < 2);
  union { u16 u[8]; bf16x8 b; } cvt;
  #pragma unroll
  for (int i = 0; i < 4; i++) {
    cvt.u[i] = act ? f2bf(tl[i]) : (u16)0;
    cvt.u[4 + i] = act ? f2bf(th[i]) : (u16)0;
  }
  return cvt.b;
}

// PV for one 16-wide d chunk: y[i] = Y[q=lane&15][d=c*16+(lane>>4)*4+i]
__device__ __forceinline__ f32x4 pv_chunk(const u16* __restrict__ vb_, size_t kvrow,
                                          int c, int lane, bf16x8 pb) {
  const int lr = lane & 15, g = lane >> 4;
  const u16* vp = vb_ + (kvrow + (size_t)(g & 1) * 8) * 64 + c * 16 + lr;
  union { u16 u[8]; bf16x8 b; } va;
  #pragma unroll
  for (int e = 0; e < 8; e++) va.u[e] = vp[(size_t)e * 64];
  f32x4 y = (f32x4){0.f, 0.f, 0.f, 0.f};
  return __builtin_amdgcn_mfma_f32_16x16x32_bf16(va.b, pb, y, 0, 0, 0);
}

// ---------------- attention levels 1..6, one wave per 16-row block ----------------
__global__ __launch_bounds__(256) void k_attn_rest(
    const u16* __restrict__ qb, const u16* __restrict__ kb, const u16* __restrict__ vb,
    u16* __restrict__ Yb, float* __restrict__ Ab) {
  const int wid = blockIdx.x * 4 + (threadIdx.x >> 6);  // 0..16127
  const int lane = threadIdx.x & 63;
  const int rb = wid * 16;                              // packed row base (levels 1..6)
  int r = rb, lnl = 11;
  while (r >= (64 << lnl)) { r -= (64 << lnl); --lnl; }
  const int posl = r & ((1 << lnl) - 1);                // block-aligned pos
  const size_t qrow = (size_t)RB1 + rb;
  const size_t kvrow = qrow - posl + ((size_t)((((posl >> 4) ^ 1)) & ((1 << (lnl - 4)) - 1)) << 4);

  f32x4 p; float asum;
  qk_softmax(qb, qrow, kb, kvrow, lane, p, asum);
  if (lane < 16) Ab[rb + lane] = asum;
  bf16x8 pb = prep_pb(p, lane);

  const int lr = lane & 15, g = lane >> 4;
  #pragma unroll
  for (int c = 0; c < 4; c++) {
    f32x4 y = pv_chunk(vb, kvrow, c, lane, pb);
    u16x4 o;
    #pragma unroll
    for (int i = 0; i < 4; i++) o[i] = f2bf(y[i]);
    *reinterpret_cast<u16x4*>(Yb + (size_t)(rb + lr) * 64 + c * 16 + g * 4) = o;
  }
}

// ---------------- attention level 0 fused with combine, one wave per block --------
__global__ __launch_bounds__(256) void k_attn0(
    const u16* __restrict__ qb, const u16* __restrict__ kb, const u16* __restrict__ vb,
    const u16* __restrict__ Yb, const float* __restrict__ Ab, float* __restrict__ out) {
  const int wid = blockIdx.x * 4 + (threadIdx.x >> 6);  // 0..16383
  const int lane = threadIdx.x & 63;
  const int rb = wid * 16;
  const int bh = rb >> 12, posb = rb & 4095;
  const size_t qrow = (size_t)rb, kvrow = (size_t)rb;   // L0: diagonal block

  f32x4 p; float asum;
  qk_softmax(qb, qrow, kb, kvrow, lane, p, asum);
  bf16x8 pb = prep_pb(p, lane);

  const int lr = lane & 15, g = lane >> 4;
  const int pos = posb + lr;                            // this lane's q-row position
  float den = asum + 1e-8f;
  int ybase[6];
  #pragma unroll
  for (int l = 1; l <= 6; l++) {
    int st = 262144 - (262144 >> (l - 1));              // packed level-l segment start
    int idx = st + (bh << (12 - l)) + (pos >> l);
    den += Ab[idx];
    ybase[l - 1] = idx;
  }
  const float inv = 1.0f / den;

  const int b = bh >> 4, h = bh & 15;
  float* op = out + ((size_t)(b * N_ + pos)) * DIM_ + h * 64;
  #pragma unroll
  for (int c = 0; c < 4; c++) {
    f32x4 y = pv_chunk(vb, kvrow, c, lane, pb);
    #pragma unroll
    for (int l = 0; l < 6; l++) {
      u16x4 cy = *reinterpret_cast<const u16x4*>(Yb + (size_t)ybase[l] * 64 + c * 16 + g * 4);
      #pragma unroll
      for (int i = 0; i < 4; i++) y[i] += bf2f(cy[i]);
    }
    f32x4 w;
    #pragma unroll
    for (int i = 0; i < 4; i++) w[i] = y[i] * inv;
    *reinterpret_cast<f32x4*>(op + c * 16 + g * 4) = w;
  }
}

extern "C" void kernel_launch(void* const* d_in, const int* in_sizes, int n_in,
                              void* d_out, int out_size, void* d_ws, size_t ws_size,
                              hipStream_t stream) {
  const float* hid = (const float*)d_in[0];
  const float* Wq = (const float*)d_in[1];
  const float* bq = (const float*)d_in[2];
  const float* Wk = (const float*)d_in[3];
  const float* bk = (const float*)d_in[4];
  const float* Wv = (const float*)d_in[5];
  const float* bv = (const float*)d_in[6];
  float* out = (float*)d_out;
  char* ws = (char*)d_ws;

  // workspace (high-water 239,599,616 B):
  //   phase 1 (GEMM):  hidb [0, 33554432)   Wt [33554432, 39845888)
  //   phase 2 (attn):  Yb   [0, 33030144)   Ab [33030144, 34062336)   <- aliases dead hidb/Wt
  //   both:            qb [39845888) kb [106430464) vb [173015040) .. 239599616
  u16* hidb = (u16*)(ws + 0);
  u16* Wt   = (u16*)(ws + 33554432);
  u16* Yb   = (u16*)(ws + 0);           // bf16, levels 1..6 packed (258048 rows x 64)
  float* Ab = (float*)(ws + 33030144);  // fp32, levels 1..6 packed (258048)
  u16* qb   = (u16*)(ws + 39845888);
  u16* kb   = (u16*)(ws + 106430464);
  u16* vb   = (u16*)(ws + 173015040);

  k_prep<<<19456, 256, 0, stream>>>(hid, hidb, Wq, Wk, Wv, Wt);
  k_qkv_gemm<<<dim3(128, 8, 1), 256, 0, stream>>>(hidb, Wt, bq, bk, bv, qb, kb, vb);
  k_attn_rest<<<4032, 256, 0, stream>>>(qb, kb, vb, Yb, Ab);
  k_attn0<<<4096, 256, 0, stream>>>(qb, kb, vb, Yb, Ab, out);
}